// Round 4
// baseline (95.321 us; speedup 1.0000x reference)
//
#include <hip/hip_runtime.h>
#include <hip/hip_bf16.h>
#include <stdint.h>

static constexpr int P_N   = 16384;
static constexpr int D_Z   = 512;
static constexpr int D_PHI = 256;
static constexpr int D_R   = 64;
static constexpr int H     = 96;    // H1 == H2
static constexpr int KP    = 832;   // 3*D_PHI + D_R

using f32x4 = __attribute__((ext_vector_type(4))) float;
using s16x8 = __attribute__((ext_vector_type(8))) short;

__device__ __forceinline__ unsigned short f2bf(float f) {
    union { float f; uint32_t u; } v; v.f = f;
    return (unsigned short)((v.u + 0x7FFFu + ((v.u >> 16) & 1u)) >> 16);
}

// packed RNE f32x2 -> bf16x2 (v_cvt_pk_bf16_f32)
__device__ __forceinline__ uint32_t pkbf2(float lo, float hi) {
    union { __hip_bfloat162 h; uint32_t u; } c;
    c.h = __float22bfloat162_rn(make_float2(lo, hi));
    return c.u;
}

// gelu(x) ~= x * sigmoid(1.5957691*(x + 0.044715 x^3))
//         =  x * rcp(1 + exp2(x*(-2.3022126 - 0.1029444 x^2)))
__device__ __forceinline__ float gelu_f(float x) {
    float x2 = x * x;
    float u  = __builtin_fmaf(-0.1029444f, x2, -2.3022126f);
    float e  = __builtin_amdgcn_exp2f(x * u);
    return x * __builtin_amdgcn_rcpf(1.0f + e);
}

// ---------------------------------------------------------------------------
// prep: blocks 0..15  : gq_pre[b][n] = g_q[b] @ W1[:512] + b1   (f32)
//       blocks 16..327: W1pT[n][k] = bf16(W1[512+k][n])   (96 x 832)
//       blocks 328..363: W2T[n][k] = bf16(W2[k][n])       (96 x 96)
// ---------------------------------------------------------------------------
__global__ __launch_bounds__(256) void prep_kernel(
    const float* __restrict__ g_q, const float* __restrict__ W1,
    const float* __restrict__ b1, const float* __restrict__ W2,
    float* __restrict__ gq_pre, unsigned short* __restrict__ W1pT,
    unsigned short* __restrict__ W2T)
{
    __shared__ float gql[D_Z];
    __shared__ float red[192];
    const int blk = blockIdx.x;
    const int t = threadIdx.x;
    if (blk < 16) {
        const int b = blk;
        for (int i = t; i < D_Z; i += 256) gql[i] = g_q[b * D_Z + i];
        __syncthreads();
        float acc = 0.f;
        if (t < 192) {
            const int n = t % 96, s = t / 96;
            const int k0 = s * 256;
            #pragma unroll 8
            for (int k = 0; k < 256; ++k)
                acc += gql[k0 + k] * W1[(k0 + k) * H + n];
            red[t] = acc;
        }
        __syncthreads();
        if (t < 96) gq_pre[b * H + t] = red[t] + red[t + 96] + b1[t];
    } else if (blk < 328) {
        const int e = (blk - 16) * 256 + t;           // < 96*832
        const int n = e / KP, k = e % KP;
        W1pT[e] = f2bf(W1[(D_Z + k) * H + n]);
    } else {
        const int e = (blk - 328) * 256 + t;          // < 96*96
        const int n = e / H, k = e % H;
        W2T[e] = f2bf(W2[k * H + n]);
    }
}

// ---------------------------------------------------------------------------
// fused3: 8 pairs x 16 b per 256-thr block (4 waves), grid 2048.
//  phase 0: feats[8][832] bf16 in LDS (stride 848)
//  phase 1: layer-1 pair GEMM, wave (kh=w&1, ng=w>>1): 3 n-frags x 13 kc;
//           partials -> y1part[kh][8][96] (summed at read time)
//  phase 2: wave w -> pairs 2w,2w+1; A-frags = bf16(gelu(gq_pre[b]+y1)) in
//           regs; MFMA vs W2T (L2/L1-resident); gelu -> dot W3 -> shfl-reduce
// ---------------------------------------------------------------------------
__global__ __launch_bounds__(256, 6) void fused3_kernel(
    const float* __restrict__ Phi, const int* __restrict__ pidx,
    const float* __restrict__ rel, const unsigned short* __restrict__ W1pT,
    const float* __restrict__ gq_pre, const unsigned short* __restrict__ W2T,
    const float* __restrict__ b2, const float* __restrict__ W3,
    const float* __restrict__ b3, float* __restrict__ out)
{
    constexpr int FS = 848;                       // feats stride (shorts)
    __shared__ __align__(16) unsigned short feats[8 * FS];
    __shared__ __align__(16) float y1part[2][8][96];
    const int t = threadIdx.x;
    const int p0 = blockIdx.x * 8;

    // phase 0: 8 pairs x 104 chunks of 8 elems
    for (int task = t; task < 832; task += 256) {
        const int pair = task / 104;
        const int k = (task - pair * 104) * 8;
        float f[8];
        if (k < 768) {
            const int2 ij = *(const int2*)(pidx + 2 * (p0 + pair));
            const int kb = k & 255;
            const float* PI = Phi + ij.x * D_PHI + kb;
            const float* PJ = Phi + ij.y * D_PHI + kb;
            float4 a0 = *(const float4*)PI, a1 = *(const float4*)(PI + 4);
            float4 c0 = *(const float4*)PJ, c1 = *(const float4*)(PJ + 4);
            if (k < 256) {
                f[0]=a0.x+c0.x; f[1]=a0.y+c0.y; f[2]=a0.z+c0.z; f[3]=a0.w+c0.w;
                f[4]=a1.x+c1.x; f[5]=a1.y+c1.y; f[6]=a1.z+c1.z; f[7]=a1.w+c1.w;
            } else if (k < 512) {
                f[0]=fabsf(a0.x-c0.x); f[1]=fabsf(a0.y-c0.y); f[2]=fabsf(a0.z-c0.z); f[3]=fabsf(a0.w-c0.w);
                f[4]=fabsf(a1.x-c1.x); f[5]=fabsf(a1.y-c1.y); f[6]=fabsf(a1.z-c1.z); f[7]=fabsf(a1.w-c1.w);
            } else {
                f[0]=a0.x*c0.x; f[1]=a0.y*c0.y; f[2]=a0.z*c0.z; f[3]=a0.w*c0.w;
                f[4]=a1.x*c1.x; f[5]=a1.y*c1.y; f[6]=a1.z*c1.z; f[7]=a1.w*c1.w;
            }
        } else {
            const float* R = rel + (p0 + pair) * D_R + (k - 768);
            float4 a0 = *(const float4*)R, a1 = *(const float4*)(R + 4);
            f[0]=a0.x; f[1]=a0.y; f[2]=a0.z; f[3]=a0.w;
            f[4]=a1.x; f[5]=a1.y; f[6]=a1.z; f[7]=a1.w;
        }
        uint4 pk;
        pk.x = pkbf2(f[0], f[1]);
        pk.y = pkbf2(f[2], f[3]);
        pk.z = pkbf2(f[4], f[5]);
        pk.w = pkbf2(f[6], f[7]);
        *(uint4*)&feats[pair * FS + k] = pk;
    }
    __syncthreads();

    const int w  = t >> 6;
    const int l  = t & 63;
    const int lr = l & 15, l4 = l >> 4;

    // phase 1: wave (kh, ng): nf in {ng*3..ng*3+2}, kc in [kh*13, kh*13+13)
    {
        const int kh = w & 1, ng = w >> 1;
        f32x4 acc[3];
        acc[0] = (f32x4){0.f,0.f,0.f,0.f};
        acc[1] = (f32x4){0.f,0.f,0.f,0.f};
        acc[2] = (f32x4){0.f,0.f,0.f,0.f};
        const unsigned short* Arow = &feats[(lr & 7) * FS + l4 * 8];
        const unsigned short* Bbase = W1pT + (ng * 48 + lr) * KP + l4 * 8;
        for (int kc = kh * 13; kc < kh * 13 + 13; ++kc) {
            const s16x8 a = *(const s16x8*)(Arow + kc * 32);
            #pragma unroll
            for (int j = 0; j < 3; ++j) {
                const s16x8 bb = *(const s16x8*)(Bbase + j * 16 * KP + kc * 32);
                acc[j] = __builtin_amdgcn_mfma_f32_16x16x32_bf16(a, bb, acc[j], 0, 0, 0);
            }
        }
        if (l4 < 2) {   // rows 8..15 duplicate rows 0..7; store 0..7 only
            #pragma unroll
            for (int j = 0; j < 3; ++j)
                #pragma unroll
                for (int r = 0; r < 4; ++r)
                    y1part[kh][l4 * 4 + r][ng * 48 + j * 16 + lr] = acc[j][r];
        }
    }
    __syncthreads();

    // phase 2a: A-fragments for layer 2, consumer layout, in registers
    s16x8 afr[2][3];
    #pragma unroll
    for (int ks = 0; ks < 3; ++ks) {
        const int c = ks * 32 + l4 * 8;
        const float* gp = gq_pre + lr * H + c;
        float4 g0 = *(const float4*)gp, g1 = *(const float4*)(gp + 4);
        #pragma unroll
        for (int mf = 0; mf < 2; ++mf) {
            const int pl = 2 * w + mf;
            const float* ya = &y1part[0][pl][c];    // broadcast reads
            const float* yb = &y1part[1][pl][c];
            float4 u0 = *(const float4*)ya, u1 = *(const float4*)(ya + 4);
            float4 v0 = *(const float4*)yb, v1 = *(const float4*)(yb + 4);
            union { s16x8 v; uint32_t u[4]; } pk;
            pk.u[0] = pkbf2(gelu_f(g0.x + u0.x + v0.x), gelu_f(g0.y + u0.y + v0.y));
            pk.u[1] = pkbf2(gelu_f(g0.z + u0.z + v0.z), gelu_f(g0.w + u0.w + v0.w));
            pk.u[2] = pkbf2(gelu_f(g1.x + u1.x + v1.x), gelu_f(g1.y + u1.y + v1.y));
            pk.u[3] = pkbf2(gelu_f(g1.z + u1.z + v1.z), gelu_f(g1.w + u1.w + v1.w));
            afr[mf][ks] = pk.v;
        }
    }

    // phase 2b: layer-2 MFMA, B from global W2T, acc init = b2
    f32x4 acc2[2][6];
    #pragma unroll
    for (int nf = 0; nf < 6; ++nf) {
        const float bv = b2[nf * 16 + lr];
        acc2[0][nf] = (f32x4){bv, bv, bv, bv};
        acc2[1][nf] = (f32x4){bv, bv, bv, bv};
    }
    #pragma unroll
    for (int ks = 0; ks < 3; ++ks) {
        #pragma unroll
        for (int nf = 0; nf < 6; ++nf) {
            const s16x8 bb = *(const s16x8*)(W2T + (nf * 16 + lr) * H + ks * 32 + l4 * 8);
            acc2[0][nf] = __builtin_amdgcn_mfma_f32_16x16x32_bf16(afr[0][ks], bb, acc2[0][nf], 0, 0, 0);
            acc2[1][nf] = __builtin_amdgcn_mfma_f32_16x16x32_bf16(afr[1][ks], bb, acc2[1][nf], 0, 0, 0);
        }
    }

    // phase 3: gelu -> dot W3 -> reduce over 16 col-lanes -> store
    float part[2][4] = {{0.f,0.f,0.f,0.f},{0.f,0.f,0.f,0.f}};
    #pragma unroll
    for (int nf = 0; nf < 6; ++nf) {
        const float wv = W3[nf * 16 + lr];
        #pragma unroll
        for (int mf = 0; mf < 2; ++mf)
            #pragma unroll
            for (int r4 = 0; r4 < 4; ++r4)
                part[mf][r4] = __builtin_fmaf(gelu_f(acc2[mf][nf][r4]), wv, part[mf][r4]);
    }
    #pragma unroll
    for (int mask = 1; mask <= 8; mask <<= 1)
        #pragma unroll
        for (int mf = 0; mf < 2; ++mf)
            #pragma unroll
            for (int r4 = 0; r4 < 4; ++r4)
                part[mf][r4] += __shfl_xor(part[mf][r4], mask, 64);
    if (lr == 0) {
        const float b3v = b3[0];
        #pragma unroll
        for (int mf = 0; mf < 2; ++mf)
            #pragma unroll
            for (int r4 = 0; r4 < 4; ++r4)
                out[(l4 * 4 + r4) * P_N + p0 + 2 * w + mf] = part[mf][r4] + b3v;
    }
}

extern "C" void kernel_launch(void* const* d_in, const int* in_sizes, int n_in,
                              void* d_out, int out_size, void* d_ws, size_t ws_size,
                              hipStream_t stream)
{
    const float* g_q  = (const float*)d_in[0];
    const float* Phi  = (const float*)d_in[1];
    const int*   pidx = (const int*)d_in[2];
    const float* rel  = (const float*)d_in[3];
    const float* W1   = (const float*)d_in[4];
    const float* b1   = (const float*)d_in[5];
    const float* W2   = (const float*)d_in[6];
    const float* b2   = (const float*)d_in[7];
    const float* W3   = (const float*)d_in[8];
    const float* b3   = (const float*)d_in[9];
    float* out = (float*)d_out;

    char* ws = (char*)d_ws;
    float*          gq_pre = (float*)(ws + 0);               // 16*96*4
    unsigned short* W1pT   = (unsigned short*)(ws + 8192);   // 96*832*2
    unsigned short* W2T    = (unsigned short*)(ws + 167936); // 96*96*2

    hipLaunchKernelGGL(prep_kernel, dim3(364), dim3(256), 0, stream,
                       g_q, W1, b1, W2, gq_pre, W1pT, W2T);
    hipLaunchKernelGGL(fused3_kernel, dim3(P_N / 8), dim3(256), 0, stream,
                       Phi, pidx, rel, W1pT, gq_pre, W2T, b2, W3, b3, out);
}

// Round 5
// 55.126 us; speedup vs baseline: 1.7291x; 1.7291x over previous
//
#include <hip/hip_runtime.h>
#include <hip/hip_bf16.h>
#include <stdint.h>

static constexpr int P_N   = 16384;
static constexpr int D_Z   = 512;
static constexpr int D_PHI = 256;
static constexpr int D_R   = 64;
static constexpr int H     = 96;    // H1 == H2
static constexpr int KP    = 832;   // 3*D_PHI + D_R

using f32x4 = __attribute__((ext_vector_type(4))) float;
using s16x8 = __attribute__((ext_vector_type(8))) short;

__device__ __forceinline__ unsigned short f2bf(float f) {
    union { float f; uint32_t u; } v; v.f = f;
    return (unsigned short)((v.u + 0x7FFFu + ((v.u >> 16) & 1u)) >> 16);
}

// packed RNE f32x2 -> bf16x2 (v_cvt_pk_bf16_f32)
__device__ __forceinline__ uint32_t pkbf2(float lo, float hi) {
    union { __hip_bfloat162 h; uint32_t u; } c;
    c.h = __float22bfloat162_rn(make_float2(lo, hi));
    return c.u;
}

// gelu(x) ~= x * sigmoid(1.5957691*(x + 0.044715 x^3))
//         =  x * rcp(1 + exp2(x*(-2.3022126 - 0.1029444 x^2)))
__device__ __forceinline__ float gelu_f(float x) {
    float x2 = x * x;
    float u  = __builtin_fmaf(-0.1029444f, x2, -2.3022126f);
    float e  = __builtin_amdgcn_exp2f(x * u);
    return x * __builtin_amdgcn_rcpf(1.0f + e);
}

// ---------------------------------------------------------------------------
// prep: blocks 0..15  : gq_pre[b][n] = g_q[b] @ W1[:512] + b1   (f32)
//       blocks 16..327: W1pT[n][k] = bf16(W1[512+k][n])   (96 x 832)
//       blocks 328..363: W2T[n][k] = bf16(W2[k][n])       (96 x 96)
// ---------------------------------------------------------------------------
__global__ __launch_bounds__(256) void prep_kernel(
    const float* __restrict__ g_q, const float* __restrict__ W1,
    const float* __restrict__ b1, const float* __restrict__ W2,
    float* __restrict__ gq_pre, unsigned short* __restrict__ W1pT,
    unsigned short* __restrict__ W2T)
{
    __shared__ float gql[D_Z];
    __shared__ float red[192];
    const int blk = blockIdx.x;
    const int t = threadIdx.x;
    if (blk < 16) {
        const int b = blk;
        for (int i = t; i < D_Z; i += 256) gql[i] = g_q[b * D_Z + i];
        __syncthreads();
        float acc = 0.f;
        if (t < 192) {
            const int n = t % 96, s = t / 96;
            const int k0 = s * 256;
            #pragma unroll 8
            for (int k = 0; k < 256; ++k)
                acc += gql[k0 + k] * W1[(k0 + k) * H + n];
            red[t] = acc;
        }
        __syncthreads();
        if (t < 96) gq_pre[b * H + t] = red[t] + red[t + 96] + b1[t];
    } else if (blk < 328) {
        const int e = (blk - 16) * 256 + t;           // < 96*832
        const int n = e / KP, k = e % KP;
        W1pT[e] = f2bf(W1[(D_Z + k) * H + n]);
    } else {
        const int e = (blk - 328) * 256 + t;          // < 96*96
        const int n = e / H, k = e % H;
        W2T[e] = f2bf(W2[k * H + n]);
    }
}

// ---------------------------------------------------------------------------
// fused4: 16 pairs x 16 b per 256-thr block (4 waves), grid 1024.
//  phase 0: feats[16][832] bf16 in LDS (stride 848)
//  phase 1: layer-1 pair GEMM over the full 16-row m-frag.
//           wave (kh=w&1, ng=w>>1): n-frags [3ng,3ng+3), kc [13kh,13kh+13)
//           partials -> y1part[kh][16][96] (summed at read time)
//  phase 2: TWO passes; pass pp: wave w -> pairs 4w+2pp, 4w+2pp+1.
//           A-frags = bf16(gelu(gq_pre[b]+y1)) built in consumer layout,
//           MFMA vs W2T (L1-resident), gelu -> dot W3 -> shfl -> out.
// ---------------------------------------------------------------------------
__global__ __launch_bounds__(256, 4) void fused4_kernel(
    const float* __restrict__ Phi, const int* __restrict__ pidx,
    const float* __restrict__ rel, const unsigned short* __restrict__ W1pT,
    const float* __restrict__ gq_pre, const unsigned short* __restrict__ W2T,
    const float* __restrict__ b2, const float* __restrict__ W3,
    const float* __restrict__ b3, float* __restrict__ out)
{
    constexpr int FS = 848;                       // feats stride (shorts)
    __shared__ __align__(16) unsigned short feats[16 * FS];
    __shared__ __align__(16) float y1part[2][16][96];
    const int t = threadIdx.x;
    const int p0 = blockIdx.x * 16;

    // phase 0: 16 pairs x 104 chunks of 8 elems
    for (int task = t; task < 1664; task += 256) {
        const int pair = task / 104;
        const int k = (task - pair * 104) * 8;
        float f[8];
        if (k < 768) {
            const int2 ij = *(const int2*)(pidx + 2 * (p0 + pair));
            const int kb = k & 255;
            const float* PI = Phi + ij.x * D_PHI + kb;
            const float* PJ = Phi + ij.y * D_PHI + kb;
            float4 a0 = *(const float4*)PI, a1 = *(const float4*)(PI + 4);
            float4 c0 = *(const float4*)PJ, c1 = *(const float4*)(PJ + 4);
            if (k < 256) {
                f[0]=a0.x+c0.x; f[1]=a0.y+c0.y; f[2]=a0.z+c0.z; f[3]=a0.w+c0.w;
                f[4]=a1.x+c1.x; f[5]=a1.y+c1.y; f[6]=a1.z+c1.z; f[7]=a1.w+c1.w;
            } else if (k < 512) {
                f[0]=fabsf(a0.x-c0.x); f[1]=fabsf(a0.y-c0.y); f[2]=fabsf(a0.z-c0.z); f[3]=fabsf(a0.w-c0.w);
                f[4]=fabsf(a1.x-c1.x); f[5]=fabsf(a1.y-c1.y); f[6]=fabsf(a1.z-c1.z); f[7]=fabsf(a1.w-c1.w);
            } else {
                f[0]=a0.x*c0.x; f[1]=a0.y*c0.y; f[2]=a0.z*c0.z; f[3]=a0.w*c0.w;
                f[4]=a1.x*c1.x; f[5]=a1.y*c1.y; f[6]=a1.z*c1.z; f[7]=a1.w*c1.w;
            }
        } else {
            const float* R = rel + (p0 + pair) * D_R + (k - 768);
            float4 a0 = *(const float4*)R, a1 = *(const float4*)(R + 4);
            f[0]=a0.x; f[1]=a0.y; f[2]=a0.z; f[3]=a0.w;
            f[4]=a1.x; f[5]=a1.y; f[6]=a1.z; f[7]=a1.w;
        }
        uint4 pk;
        pk.x = pkbf2(f[0], f[1]);
        pk.y = pkbf2(f[2], f[3]);
        pk.z = pkbf2(f[4], f[5]);
        pk.w = pkbf2(f[6], f[7]);
        *(uint4*)&feats[pair * FS + k] = pk;
    }
    __syncthreads();

    const int w  = t >> 6;
    const int l  = t & 63;
    const int lr = l & 15, l4 = l >> 4;

    // phase 1: wave (kh, ng): 3 n-frags x 13 kc over all 16 pair-rows
    {
        const int kh = w & 1, ng = w >> 1;
        f32x4 acc[3];
        acc[0] = (f32x4){0.f,0.f,0.f,0.f};
        acc[1] = (f32x4){0.f,0.f,0.f,0.f};
        acc[2] = (f32x4){0.f,0.f,0.f,0.f};
        const unsigned short* Arow  = &feats[lr * FS + l4 * 8];
        const unsigned short* Bbase = W1pT + (ng * 48 + lr) * KP + l4 * 8;
        for (int kc = kh * 13; kc < kh * 13 + 13; ++kc) {
            const s16x8 a = *(const s16x8*)(Arow + kc * 32);
            #pragma unroll
            for (int j = 0; j < 3; ++j) {
                const s16x8 bb = *(const s16x8*)(Bbase + j * 16 * KP + kc * 32);
                acc[j] = __builtin_amdgcn_mfma_f32_16x16x32_bf16(a, bb, acc[j], 0, 0, 0);
            }
        }
        #pragma unroll
        for (int j = 0; j < 3; ++j)
            #pragma unroll
            for (int r = 0; r < 4; ++r)
                y1part[kh][l4 * 4 + r][ng * 48 + j * 16 + lr] = acc[j][r];
    }
    __syncthreads();

    // phase 2: two passes of 2 pairs per wave
    const float b3v = b3[0];
    #pragma unroll
    for (int pp = 0; pp < 2; ++pp) {
        const int plbase = w * 4 + pp * 2;

        // 2a: A-fragments in consumer layout (row lr = b)
        s16x8 afr[2][3];
        #pragma unroll
        for (int ks = 0; ks < 3; ++ks) {
            const int c = ks * 32 + l4 * 8;
            const float* gp = gq_pre + lr * H + c;
            float4 g0 = *(const float4*)gp, g1 = *(const float4*)(gp + 4);
            #pragma unroll
            for (int mf = 0; mf < 2; ++mf) {
                const int pl = plbase + mf;
                const float* ya = &y1part[0][pl][c];    // broadcast reads
                const float* yb = &y1part[1][pl][c];
                float4 u0 = *(const float4*)ya, u1 = *(const float4*)(ya + 4);
                float4 v0 = *(const float4*)yb, v1 = *(const float4*)(yb + 4);
                union { s16x8 v; uint32_t u[4]; } pk;
                pk.u[0] = pkbf2(gelu_f(g0.x + u0.x + v0.x), gelu_f(g0.y + u0.y + v0.y));
                pk.u[1] = pkbf2(gelu_f(g0.z + u0.z + v0.z), gelu_f(g0.w + u0.w + v0.w));
                pk.u[2] = pkbf2(gelu_f(g1.x + u1.x + v1.x), gelu_f(g1.y + u1.y + v1.y));
                pk.u[3] = pkbf2(gelu_f(g1.z + u1.z + v1.z), gelu_f(g1.w + u1.w + v1.w));
                afr[mf][ks] = pk.v;
            }
        }

        // 2b: layer-2 MFMA, B from global W2T (L1-hot), acc init = b2
        f32x4 acc2[2][6];
        #pragma unroll
        for (int nf = 0; nf < 6; ++nf) {
            const float bv = b2[nf * 16 + lr];
            acc2[0][nf] = (f32x4){bv, bv, bv, bv};
            acc2[1][nf] = (f32x4){bv, bv, bv, bv};
        }
        #pragma unroll
        for (int ks = 0; ks < 3; ++ks) {
            #pragma unroll
            for (int nf = 0; nf < 6; ++nf) {
                const s16x8 bb = *(const s16x8*)(W2T + (nf * 16 + lr) * H + ks * 32 + l4 * 8);
                acc2[0][nf] = __builtin_amdgcn_mfma_f32_16x16x32_bf16(afr[0][ks], bb, acc2[0][nf], 0, 0, 0);
                acc2[1][nf] = __builtin_amdgcn_mfma_f32_16x16x32_bf16(afr[1][ks], bb, acc2[1][nf], 0, 0, 0);
            }
        }

        // 2c: gelu -> dot W3 -> reduce over 16 col-lanes -> store
        float part[2][4] = {{0.f,0.f,0.f,0.f},{0.f,0.f,0.f,0.f}};
        #pragma unroll
        for (int nf = 0; nf < 6; ++nf) {
            const float wv = W3[nf * 16 + lr];
            #pragma unroll
            for (int mf = 0; mf < 2; ++mf)
                #pragma unroll
                for (int r4 = 0; r4 < 4; ++r4)
                    part[mf][r4] = __builtin_fmaf(gelu_f(acc2[mf][nf][r4]), wv, part[mf][r4]);
        }
        #pragma unroll
        for (int mask = 1; mask <= 8; mask <<= 1)
            #pragma unroll
            for (int mf = 0; mf < 2; ++mf)
                #pragma unroll
                for (int r4 = 0; r4 < 4; ++r4)
                    part[mf][r4] += __shfl_xor(part[mf][r4], mask, 64);
        if (lr == 0) {
            #pragma unroll
            for (int mf = 0; mf < 2; ++mf)
                #pragma unroll
                for (int r4 = 0; r4 < 4; ++r4)
                    out[(l4 * 4 + r4) * P_N + p0 + plbase + mf] = part[mf][r4] + b3v;
        }
    }
}

extern "C" void kernel_launch(void* const* d_in, const int* in_sizes, int n_in,
                              void* d_out, int out_size, void* d_ws, size_t ws_size,
                              hipStream_t stream)
{
    const float* g_q  = (const float*)d_in[0];
    const float* Phi  = (const float*)d_in[1];
    const int*   pidx = (const int*)d_in[2];
    const float* rel  = (const float*)d_in[3];
    const float* W1   = (const float*)d_in[4];
    const float* b1   = (const float*)d_in[5];
    const float* W2   = (const float*)d_in[6];
    const float* b2   = (const float*)d_in[7];
    const float* W3   = (const float*)d_in[8];
    const float* b3   = (const float*)d_in[9];
    float* out = (float*)d_out;

    char* ws = (char*)d_ws;
    float*          gq_pre = (float*)(ws + 0);               // 16*96*4
    unsigned short* W1pT   = (unsigned short*)(ws + 8192);   // 96*832*2
    unsigned short* W2T    = (unsigned short*)(ws + 167936); // 96*96*2

    hipLaunchKernelGGL(prep_kernel, dim3(364), dim3(256), 0, stream,
                       g_q, W1, b1, W2, gq_pre, W1pT, W2T);
    hipLaunchKernelGGL(fused4_kernel, dim3(P_N / 16), dim3(256), 0, stream,
                       Phi, pidx, rel, W1pT, gq_pre, W2T, b2, W3, b3, out);
}

// Round 6
// 46.683 us; speedup vs baseline: 2.0419x; 1.1809x over previous
//
#include <hip/hip_runtime.h>
#include <hip/hip_bf16.h>
#include <stdint.h>

static constexpr int P_N   = 16384;
static constexpr int D_Z   = 512;
static constexpr int D_PHI = 256;
static constexpr int D_R   = 64;
static constexpr int H     = 96;    // H1 == H2
static constexpr int KP    = 832;   // 3*D_PHI + D_R

using f32x4 = __attribute__((ext_vector_type(4))) float;
using s16x8 = __attribute__((ext_vector_type(8))) short;

__device__ __forceinline__ unsigned short f2bf(float f) {
    union { float f; uint32_t u; } v; v.f = f;
    return (unsigned short)((v.u + 0x7FFFu + ((v.u >> 16) & 1u)) >> 16);
}

// packed RNE f32x2 -> bf16x2 (v_cvt_pk_bf16_f32)
__device__ __forceinline__ uint32_t pkbf2(float lo, float hi) {
    union { __hip_bfloat162 h; uint32_t u; } c;
    c.h = __float22bfloat162_rn(make_float2(lo, hi));
    return c.u;
}

// gelu(x) ~= x * sigmoid(1.5957691*(x + 0.044715 x^3))
//         =  x * rcp(1 + exp2(x*(-2.3022126 - 0.1029444 x^2)))
__device__ __forceinline__ float gelu_f(float x) {
    float x2 = x * x;
    float u  = __builtin_fmaf(-0.1029444f, x2, -2.3022126f);
    float e  = __builtin_amdgcn_exp2f(x * u);
    return x * __builtin_amdgcn_rcpf(1.0f + e);
}

// ---------------------------------------------------------------------------
// prep: fragment-contiguous weight layouts so every fused-kernel B-load is
//       base + lane*16B (fully coalesced).
//  blocks 0..15  : gqfrag[(nn>>5)*64 + ((nn>>3)&3)*16 + b]*8 + (nn&7)
//                  = g_q[b] @ W1[:512] + b1          (f32, 3*64*8)
//  blocks 16..327: W1frag[((nf*26+kc)*64 + l)*8 + ke] = bf16(W1[512+k][n])
//                  n = nf*16 + (l&15), k = kc*32 + (l>>4)*8 + ke
//  blocks 328..363: W2frag[((nf*3+ks)*64 + l)*8 + ke] = bf16(W2[k][n])
//                  n = nf*16 + (l&15), k = ks*32 + (l>>4)*8 + ke
// ---------------------------------------------------------------------------
__global__ __launch_bounds__(256) void prep_kernel(
    const float* __restrict__ g_q, const float* __restrict__ W1,
    const float* __restrict__ b1, const float* __restrict__ W2,
    float* __restrict__ gqfrag, unsigned short* __restrict__ W1frag,
    unsigned short* __restrict__ W2frag)
{
    __shared__ float gql[D_Z];
    __shared__ float red[192];
    const int blk = blockIdx.x;
    const int t = threadIdx.x;
    if (blk < 16) {
        const int b = blk;
        for (int i = t; i < D_Z; i += 256) gql[i] = g_q[b * D_Z + i];
        __syncthreads();
        float acc = 0.f;
        if (t < 192) {
            const int n = t % 96, s = t / 96;
            const int k0 = s * 256;
            #pragma unroll 8
            for (int k = 0; k < 256; ++k)
                acc += gql[k0 + k] * W1[(k0 + k) * H + n];
            red[t] = acc;
        }
        __syncthreads();
        if (t < 96) {
            const float v = red[t] + red[t + 96] + b1[t];
            const int dst = ((t >> 5) * 64 + ((t >> 3) & 3) * 16 + b) * 8 + (t & 7);
            gqfrag[dst] = v;
        }
    } else if (blk < 328) {
        const int e = (blk - 16) * 256 + t;           // < 96*832
        const int n = e / KP, k = e % KP;
        const int nf = n >> 4, lr = n & 15;
        const int kc = k >> 5, l4 = (k >> 3) & 3, ke = k & 7;
        W1frag[((nf * 26 + kc) * 64 + l4 * 16 + lr) * 8 + ke] =
            f2bf(W1[(D_Z + k) * H + n]);
    } else {
        const int e = (blk - 328) * 256 + t;          // < 96*96
        const int n = e / H, k = e % H;
        const int nf = n >> 4, lr = n & 15;
        const int ks = k >> 5, l4 = (k >> 3) & 3, ke = k & 7;
        W2frag[((nf * 3 + ks) * 64 + l4 * 16 + lr) * 8 + ke] =
            f2bf(W2[k * H + n]);
    }
}

// ---------------------------------------------------------------------------
// fused5: 8 pairs x 16 b per 256-thr block (4 waves), grid 2048
//         (4 resident + 4 queued per CU -> staggered phases).
//  phase 0: feats[8][832] bf16 in LDS (stride 840)
//  phase 1: wave (kh=w&1, ng=w>>1): n-frags [3ng,3ng+3), kc [13kh,13kh+13);
//           A rows = pair lr&7 (dup); partials -> y1part[kh][8][96] f32
//  phase 2: wave w -> pairs 2w, 2w+1. A-frags = bf16(gelu(gq+y1)) in
//           consumer layout; MFMA vs W2frag; gelu -> dot W3 -> shfl -> out
// ---------------------------------------------------------------------------
__global__ __launch_bounds__(256, 4) void fused5_kernel(
    const float* __restrict__ Phi, const int* __restrict__ pidx,
    const float* __restrict__ rel, const unsigned short* __restrict__ W1frag,
    const float* __restrict__ gqfrag, const unsigned short* __restrict__ W2frag,
    const float* __restrict__ b2, const float* __restrict__ W3,
    const float* __restrict__ b3, float* __restrict__ out)
{
    constexpr int FS = 840;                       // feats stride (shorts)
    __shared__ __align__(16) unsigned short feats[8 * FS];
    __shared__ __align__(16) float y1part[2][8][96];
    const int t = threadIdx.x;
    const int p0 = blockIdx.x * 8;

    // phase 0: 8 pairs x 104 chunks of 8 elems
    for (int task = t; task < 832; task += 256) {
        const int pair = task / 104;
        const int k = (task - pair * 104) * 8;
        float f[8];
        if (k < 768) {
            const int2 ij = *(const int2*)(pidx + 2 * (p0 + pair));
            const int kb = k & 255;
            const float* PI = Phi + ij.x * D_PHI + kb;
            const float* PJ = Phi + ij.y * D_PHI + kb;
            float4 a0 = *(const float4*)PI, a1 = *(const float4*)(PI + 4);
            float4 c0 = *(const float4*)PJ, c1 = *(const float4*)(PJ + 4);
            if (k < 256) {
                f[0]=a0.x+c0.x; f[1]=a0.y+c0.y; f[2]=a0.z+c0.z; f[3]=a0.w+c0.w;
                f[4]=a1.x+c1.x; f[5]=a1.y+c1.y; f[6]=a1.z+c1.z; f[7]=a1.w+c1.w;
            } else if (k < 512) {
                f[0]=fabsf(a0.x-c0.x); f[1]=fabsf(a0.y-c0.y); f[2]=fabsf(a0.z-c0.z); f[3]=fabsf(a0.w-c0.w);
                f[4]=fabsf(a1.x-c1.x); f[5]=fabsf(a1.y-c1.y); f[6]=fabsf(a1.z-c1.z); f[7]=fabsf(a1.w-c1.w);
            } else {
                f[0]=a0.x*c0.x; f[1]=a0.y*c0.y; f[2]=a0.z*c0.z; f[3]=a0.w*c0.w;
                f[4]=a1.x*c1.x; f[5]=a1.y*c1.y; f[6]=a1.z*c1.z; f[7]=a1.w*c1.w;
            }
        } else {
            const float* R = rel + (p0 + pair) * D_R + (k - 768);
            float4 a0 = *(const float4*)R, a1 = *(const float4*)(R + 4);
            f[0]=a0.x; f[1]=a0.y; f[2]=a0.z; f[3]=a0.w;
            f[4]=a1.x; f[5]=a1.y; f[6]=a1.z; f[7]=a1.w;
        }
        uint4 pk;
        pk.x = pkbf2(f[0], f[1]);
        pk.y = pkbf2(f[2], f[3]);
        pk.z = pkbf2(f[4], f[5]);
        pk.w = pkbf2(f[6], f[7]);
        *(uint4*)&feats[pair * FS + k] = pk;
    }
    __syncthreads();

    const int w  = t >> 6;
    const int l  = t & 63;
    const int lr = l & 15, l4 = l >> 4;

    // phase 1: wave (kh, ng): 3 n-frags x 13 kc, A rows = pairs (lr&7 dup)
    {
        const int kh = w & 1, ng = w >> 1;
        f32x4 acc[3];
        acc[0] = (f32x4){0.f,0.f,0.f,0.f};
        acc[1] = (f32x4){0.f,0.f,0.f,0.f};
        acc[2] = (f32x4){0.f,0.f,0.f,0.f};
        const unsigned short* Arow = &feats[(lr & 7) * FS + l4 * 8];
        const int kc0 = kh * 13;
        for (int i = 0; i < 13; ++i) {
            const int kc = kc0 + i;
            const s16x8 a = *(const s16x8*)(Arow + kc * 32);
            #pragma unroll
            for (int j = 0; j < 3; ++j) {
                const s16x8 bb = *(const s16x8*)(W1frag +
                    (((ng * 3 + j) * 26 + kc) * 64 + l) * 8);
                acc[j] = __builtin_amdgcn_mfma_f32_16x16x32_bf16(a, bb, acc[j], 0, 0, 0);
            }
        }
        if (l4 < 2) {   // rows 8..15 duplicate rows 0..7
            #pragma unroll
            for (int j = 0; j < 3; ++j)
                #pragma unroll
                for (int r = 0; r < 4; ++r)
                    y1part[kh][l4 * 4 + r][ng * 48 + j * 16 + lr] = acc[j][r];
        }
    }
    __syncthreads();

    // phase 2a: A-fragments in consumer layout (row lr = b), pairs 2w,2w+1
    s16x8 afr[2][3];
    #pragma unroll
    for (int ks = 0; ks < 3; ++ks) {
        const int c = ks * 32 + l4 * 8;
        const float* gp = gqfrag + (ks * 64 + l) * 8;
        float4 g0 = *(const float4*)gp, g1 = *(const float4*)(gp + 4);
        #pragma unroll
        for (int mf = 0; mf < 2; ++mf) {
            const int pl = 2 * w + mf;
            const float* ya = &y1part[0][pl][c];    // broadcast reads
            const float* yb = &y1part[1][pl][c];
            float4 u0 = *(const float4*)ya, u1 = *(const float4*)(ya + 4);
            float4 v0 = *(const float4*)yb, v1 = *(const float4*)(yb + 4);
            union { s16x8 v; uint32_t u[4]; } pk;
            pk.u[0] = pkbf2(gelu_f(g0.x + u0.x + v0.x), gelu_f(g0.y + u0.y + v0.y));
            pk.u[1] = pkbf2(gelu_f(g0.z + u0.z + v0.z), gelu_f(g0.w + u0.w + v0.w));
            pk.u[2] = pkbf2(gelu_f(g1.x + u1.x + v1.x), gelu_f(g1.y + u1.y + v1.y));
            pk.u[3] = pkbf2(gelu_f(g1.z + u1.z + v1.z), gelu_f(g1.w + u1.w + v1.w));
            afr[mf][ks] = pk.v;
        }
    }

    // phase 2b: layer-2 MFMA vs W2frag (L1-hot), acc init = b2
    f32x4 acc2[2][6];
    #pragma unroll
    for (int nf = 0; nf < 6; ++nf) {
        const float bv = b2[nf * 16 + lr];
        acc2[0][nf] = (f32x4){bv, bv, bv, bv};
        acc2[1][nf] = (f32x4){bv, bv, bv, bv};
    }
    #pragma unroll
    for (int ks = 0; ks < 3; ++ks) {
        #pragma unroll
        for (int nf = 0; nf < 6; ++nf) {
            const s16x8 bb = *(const s16x8*)(W2frag + ((nf * 3 + ks) * 64 + l) * 8);
            acc2[0][nf] = __builtin_amdgcn_mfma_f32_16x16x32_bf16(afr[0][ks], bb, acc2[0][nf], 0, 0, 0);
            acc2[1][nf] = __builtin_amdgcn_mfma_f32_16x16x32_bf16(afr[1][ks], bb, acc2[1][nf], 0, 0, 0);
        }
    }

    // phase 3: gelu -> dot W3 -> reduce over 16 col-lanes -> store
    float part[2][4] = {{0.f,0.f,0.f,0.f},{0.f,0.f,0.f,0.f}};
    #pragma unroll
    for (int nf = 0; nf < 6; ++nf) {
        const float wv = W3[nf * 16 + lr];
        #pragma unroll
        for (int mf = 0; mf < 2; ++mf)
            #pragma unroll
            for (int r4 = 0; r4 < 4; ++r4)
                part[mf][r4] = __builtin_fmaf(gelu_f(acc2[mf][nf][r4]), wv, part[mf][r4]);
    }
    #pragma unroll
    for (int mask = 1; mask <= 8; mask <<= 1)
        #pragma unroll
        for (int mf = 0; mf < 2; ++mf)
            #pragma unroll
            for (int r4 = 0; r4 < 4; ++r4)
                part[mf][r4] += __shfl_xor(part[mf][r4], mask, 64);
    if (lr == 0) {
        const float b3v = b3[0];
        #pragma unroll
        for (int mf = 0; mf < 2; ++mf)
            #pragma unroll
            for (int r4 = 0; r4 < 4; ++r4)
                out[(l4 * 4 + r4) * P_N + p0 + 2 * w + mf] = part[mf][r4] + b3v;
    }
}

extern "C" void kernel_launch(void* const* d_in, const int* in_sizes, int n_in,
                              void* d_out, int out_size, void* d_ws, size_t ws_size,
                              hipStream_t stream)
{
    const float* g_q  = (const float*)d_in[0];
    const float* Phi  = (const float*)d_in[1];
    const int*   pidx = (const int*)d_in[2];
    const float* rel  = (const float*)d_in[3];
    const float* W1   = (const float*)d_in[4];
    const float* b1   = (const float*)d_in[5];
    const float* W2   = (const float*)d_in[6];
    const float* b2   = (const float*)d_in[7];
    const float* W3   = (const float*)d_in[8];
    const float* b3   = (const float*)d_in[9];
    float* out = (float*)d_out;

    char* ws = (char*)d_ws;
    float*          gqfrag = (float*)(ws + 0);               // 3*64*8 f32 = 6KB
    unsigned short* W1frag = (unsigned short*)(ws + 8192);   // 96*832*2
    unsigned short* W2frag = (unsigned short*)(ws + 167936); // 96*96*2

    hipLaunchKernelGGL(prep_kernel, dim3(364), dim3(256), 0, stream,
                       g_q, W1, b1, W2, gqfrag, W1frag, W2frag);
    hipLaunchKernelGGL(fused5_kernel, dim3(P_N / 8), dim3(256), 0, stream,
                       Phi, pidx, rel, W1frag, gqfrag, W2frag, b2, W3, b3, out);
}